// Round 10
// baseline (514.218 us; speedup 1.0000x reference)
//
#include <hip/hip_runtime.h>
#include <hip/hip_bf16.h>

// Problem: B=8, S=4096, D=768
//   y = tanh(x @ W); scores = y . v; w = softmax_S(scores); out = sum_s w * x
constexpr int Bb = 8;
constexpr int Ss = 4096;
constexpr int Dd = 768;
constexpr int Mm = Bb * Ss;      // 32768 rows

typedef __bf16 bf16x8 __attribute__((ext_vector_type(8)));
typedef __bf16 bf16x4 __attribute__((ext_vector_type(4)));
typedef float f32x4 __attribute__((ext_vector_type(4)));

__device__ __forceinline__ float fast_tanh(float x) {
    return 1.f - 2.f / (__expf(2.f * x) + 1.f);
}

__device__ __forceinline__ void load_lds16(const void* g, void* l) {
    __builtin_amdgcn_global_load_lds(
        (const __attribute__((address_space(1))) unsigned int*)g,
        (__attribute__((address_space(3))) unsigned int*)l, 16, 0, 0);
}

// ---------------- Kernel 0 (merged): blocks 0..575 transpose W fp32 ->
// Wt[n][k] bf16 with the bank-swizzle baked into the layout (16B slot s ->
// s ^ ((n>>1)&3) within each 64B k-chunk; measured 0-conflict on B reads).
// blocks 576..: x fp32 -> xb bf16 with the SAME swizzle baked per-row
// (slot s -> s ^ ((m>>1)&3)) so the gemm A-read is conflict-free too
// (round-9: fixed the measured 2,359,296 conflict-cycles of linear xb).
__global__ __launch_bounds__(256) void convWX(const float* __restrict__ W,
                                              __bf16* __restrict__ Wt,
                                              const float* __restrict__ x,
                                              __bf16* __restrict__ xb) {
    const int bid = blockIdx.x;
    if (bid < 576) {                      // ---- convW tile (24 x 24 grid)
        __shared__ float tile[32][33];
        const int tx = threadIdx.x & 31;
        const int ty = threadIdx.x >> 5;
        const int kb = (bid % 24) * 32;
        const int nb = (bid / 24) * 32;
#pragma unroll
        for (int i = 0; i < 32; i += 8)
            tile[ty + i][tx] = W[(size_t)(kb + ty + i) * Dd + nb + tx];
        __syncthreads();
#pragma unroll
        for (int i = 0; i < 32; i += 8) {
            const int n = nb + ty + i;
            const int txs = (tx & 7) | ((((tx >> 3) & 3) ^ ((n >> 1) & 3)) << 3);
            Wt[(size_t)n * Dd + kb + txs] = (__bf16)tile[tx][ty + i];
        }
    } else {                              // ---- convX chunk (12288 blocks)
        const size_t i = ((size_t)(bid - 576) * 256 + threadIdx.x) * 8;
        const int m = (int)(i / Dd);
        const int k = (int)(i % Dd);
        const int sl = (k >> 3) & 3;      // logical 16B slot in 64B chunk
        const int dk = (k & ~31) | (((sl ^ ((m >> 1) & 3)) << 3));
        const float4 a = *(const float4*)(x + i);
        const float4 b = *(const float4*)(x + i + 4);
        bf16x8 p;
        p[0] = (__bf16)a.x; p[1] = (__bf16)a.y; p[2] = (__bf16)a.z; p[3] = (__bf16)a.w;
        p[4] = (__bf16)b.x; p[5] = (__bf16)b.y; p[6] = (__bf16)b.z; p[7] = (__bf16)b.w;
        *(bf16x8*)(xb + (size_t)m * Dd + dk) = p;
    }
}

// ---------------- Kernel 1: scores3[nb][m] = sum_n v[n]*tanh( (x@W)[m][n] )
// Round-10 change: 2-DEEP LDS (50 KB) -> 3 blocks/CU, grid 768 = exactly
// 3/CU, ZERO TAIL (round-9's 3-deep/75KB ran 2 resident + a 1-block/CU tail
// round for 1/3 of the work). Schedule is the proven m97 shape: issue
// S(k+1) right after the barrier, vmcnt(0) drain at each step top (per-wave
// drain before barrier => all staging writes visible after barrier; 2-buffer
// WAR hazard closed by the barrier itself). Counted-vmcnt traded for +50%
// occupancy: at 3 blocks/CU the other blocks' waves hide the drain (m114).
// Per K-step: 3 gl_lds + 8 ds_read_b128 + 16 MFMA; both operands read at
// the baked-swizzle slot (measured 0 conflicts); setprio; XCD swizzle.
__global__ __launch_bounds__(512, 6) void scores_gemm(
    const __bf16* __restrict__ xb, const __bf16* __restrict__ Wt,
    const float* __restrict__ v, float* __restrict__ scores3) {
    __shared__ __bf16 As[2][128 * 32];    // 2 x 8 KB
    __shared__ __bf16 Bs[2][256 * 32];    // 2 x 16 KB
    __shared__ float ssc[8][64];          // 2 KB   -> 50 KB total

    const int t = threadIdx.x;
    // XCD swizzle: 768 blocks, 8 XCDs -> XCD x owns ids [x*96,(x+1)*96)
    const int id = blockIdx.x;
    const int ids = ((id & 7) * 96) + (id >> 3);
    const int mb = ids / 3;               // 0..255
    const int nb = ids - mb * 3;          // 0..2
    const int lane = t & 63;
    const int wave = t >> 6;
    const int wm = wave >> 2;             // 0..1 (64-row half)
    const int wn = wave & 3;              // 0..3 (64-col slice)
    const int quad = lane >> 4;
    const int lid = lane & 15;
    const int rslot = ((quad ^ ((lid >> 1) & 3)) * 8);   // A+B read swizzle

    // A staging: 1 shot of 512x16B over the [128 x 64B] tile (xb stored in
    // phys-slot order -> linear gl_lds source).
    const __bf16* axg = xb + (size_t)(mb * 128 + (t >> 2)) * Dd + (t & 3) * 8;
    const int awl = t * 8;                // bf16 index into As[buf]

    // B staging: 2 shots of 512x16B over the [256 x 64B] tile.
    const __bf16* bgp[2];
    int blp[2];
#pragma unroll
    for (int j = 0; j < 2; ++j) {
        const int flat = j * 8192 + t * 16;   // bytes
        const int col = flat >> 6;
        bgp[j] = Wt + (size_t)(nb * 256 + col) * Dd + ((flat & 63) >> 1);
        blp[j] = flat >> 1;                   // bf16 index into Bs[buf]
    }

    f32x4 acc[4][4];
#pragma unroll
    for (int tm = 0; tm < 4; ++tm)
#pragma unroll
        for (int nt = 0; nt < 4; ++nt) acc[tm][nt] = (f32x4){0.f, 0.f, 0.f, 0.f};

    // ---- prologue: S(0) -> buf 0
    load_lds16(axg, &As[0][awl]);
#pragma unroll
    for (int j = 0; j < 2; ++j) load_lds16(bgp[j], &Bs[0][blp[j]]);

#pragma unroll
    for (int k = 0; k < 24; ++k) {
        const int p = k & 1;
        // Drain own staging loads (S(k)); barrier publishes buf p to all.
        asm volatile("s_waitcnt vmcnt(0)" ::: "memory");
        __builtin_amdgcn_sched_barrier(0);
        __builtin_amdgcn_s_barrier();
        __builtin_amdgcn_sched_barrier(0);

        if (k < 23) {                     // S(k+1) -> buf 1-p (flies over compute)
            load_lds16(axg + (k + 1) * 32, &As[1 - p][awl]);
#pragma unroll
            for (int j = 0; j < 2; ++j)
                load_lds16(bgp[j] + (k + 1) * 32, &Bs[1 - p][blp[j]]);
        }
        __builtin_amdgcn_sched_barrier(0);

        bf16x8 af[4], bfr[4];
#pragma unroll
        for (int tm = 0; tm < 4; ++tm)
            af[tm] = *(const bf16x8*)(&As[p][(wm * 64 + tm * 16 + lid) * 32 + rslot]);
#pragma unroll
        for (int nt = 0; nt < 4; ++nt)
            bfr[nt] = *(const bf16x8*)(&Bs[p][(wn * 64 + nt * 16 + lid) * 32 + rslot]);

        __builtin_amdgcn_s_setprio(1);
#pragma unroll
        for (int tm = 0; tm < 4; ++tm)
#pragma unroll
            for (int nt = 0; nt < 4; ++nt)
                acc[tm][nt] = __builtin_amdgcn_mfma_f32_16x16x32_bf16(af[tm], bfr[nt], acc[tm][nt], 0, 0, 0);
        __builtin_amdgcn_s_setprio(0);
    }

    // ---- epilogue: fold tanh*v over this block's 256 cols, reduce to rows
    float vv[4];
#pragma unroll
    for (int nt = 0; nt < 4; ++nt)
        vv[nt] = v[nb * 256 + wn * 64 + nt * 16 + lid];

#pragma unroll
    for (int tm = 0; tm < 4; ++tm)
#pragma unroll
        for (int r = 0; r < 4; ++r) {
            float s = 0.f;
#pragma unroll
            for (int nt = 0; nt < 4; ++nt) s += vv[nt] * fast_tanh(acc[tm][nt][r]);
            // C layout: col=lid, row=quad*4+r
            s += __shfl_xor(s, 1);
            s += __shfl_xor(s, 2);
            s += __shfl_xor(s, 4);
            s += __shfl_xor(s, 8);
            if (lid == 0) ssc[wave][tm * 16 + quad * 4 + r] = s;
        }
    __syncthreads();
    if (t < 128) {
        const int wmh = t >> 6;           // which 64-row half
        const int rl = t & 63;
        float s = 0.f;
#pragma unroll
        for (int ww = 0; ww < 4; ++ww) s += ssc[wmh * 4 + ww][rl];
        scores3[(size_t)nb * Mm + mb * 128 + t] = s;   // no atomics, no memset
    }
}

// ---------------- Kernel 2: pool with INLINE exp (no separate softmax pass,
// no fences/atomics). Scores structurally bounded (|s| <= ||v||_1 ~ 6.2) so
// exp without max-subtraction is fp32-safe (verified rounds 7-9). Reads xb
// (bf16, 50 MB; swizzle undone via XOR on the read index, coalescing kept).
__global__ __launch_bounds__(192) void pool1e(const __bf16* __restrict__ xb,
                                              const float* __restrict__ scores3,
                                              float* __restrict__ partial,
                                              float* __restrict__ esum) {
    const int b = blockIdx.y;
    const int c = blockIdx.x;            // 128 chunks x 32 rows
    const int t = threadIdx.x;           // owns 4 d-cols at d0 = t*4
    __shared__ float we[32];

    if (t < 32) {
        const size_t i = (size_t)b * Ss + c * 32 + t;
        we[t] = __expf(scores3[i] + scores3[Mm + i] + scores3[2 * Mm + i]);
    }
    __syncthreads();

    const int d0 = t * 4;
    const int kc = d0 & ~31;             // 64B-chunk base (32 bf16)
    const int sl = (d0 >> 3) & 3;        // logical 16B slot
    const int w8 = d0 & 7;               // offset within slot (0 or 4)
    const int m0 = b * Ss + c * 32;      // global row of i=0
    const __bf16* base = xb + (size_t)m0 * Dd;

    float4 acc = make_float4(0.f, 0.f, 0.f, 0.f);
#pragma unroll 8
    for (int i = 0; i < 32; ++i) {
        const float ww = we[i];
        const int phys = kc + ((sl ^ (((m0 + i) >> 1) & 3)) << 3) + w8;
        const bf16x4 xv = *(const bf16x4*)(base + (size_t)i * Dd + phys);
        acc.x += ww * (float)xv[0];
        acc.y += ww * (float)xv[1];
        acc.z += ww * (float)xv[2];
        acc.w += ww * (float)xv[3];
    }
    *(float4*)(partial + ((size_t)(b * 128 + c)) * Dd + d0) = acc;
    if (t == 0) {
        float s = 0.f;
#pragma unroll
        for (int i = 0; i < 32; ++i) s += we[i];
        esum[b * 128 + c] = s;
    }
}

// ---------------- Kernel 3: out[b][d] = (sum_c partial[b][c][d]) / sum esum.
// grid (6 d-segments, B) = 48 blocks x 128 thr; each block also reduces the
// 128 esums for its batch (tiny, L2-hit).
__global__ __launch_bounds__(128) void pool2(const float* __restrict__ partial,
                                             const float* __restrict__ esum,
                                             float* __restrict__ out) {
    const int b = blockIdx.y;
    const int t = threadIdx.x;
    const int d = blockIdx.x * 128 + t;   // 0..767

    float es = 0.f;
    if (t < 64) {
        es = esum[b * 128 + t] + esum[b * 128 + 64 + t];
        es += __shfl_xor(es, 1);
        es += __shfl_xor(es, 2);
        es += __shfl_xor(es, 4);
        es += __shfl_xor(es, 8);
        es += __shfl_xor(es, 16);
        es += __shfl_xor(es, 32);
    }
    __shared__ float esT;
    if (t == 0) esT = es;
    __syncthreads();
    const float inv = 1.f / esT;

    float s = 0.f;
#pragma unroll 8
    for (int c = 0; c < 128; ++c) s += partial[((size_t)(b * 128 + c)) * Dd + d];
    out[(size_t)b * Dd + d] = s * inv;
}

extern "C" void kernel_launch(void* const* d_in, const int* in_sizes, int n_in,
                              void* d_out, int out_size, void* d_ws, size_t ws_size,
                              hipStream_t stream) {
    (void)in_sizes; (void)n_in; (void)ws_size; (void)out_size;
    const float* x = (const float*)d_in[0];
    const float* v = (const float*)d_in[1];
    const float* W = (const float*)d_in[2];

    char* ws = (char*)d_ws;
    // layout: Wt | scores3 | esum | partial | xb   (~55 MB)
    constexpr size_t OFF_WT = 0;                         // 1,179,648 B
    constexpr size_t OFF_SC = 1179648;                   //   393,216 B
    constexpr size_t OFF_ES = OFF_SC + 393216;           //     4,096 B
    constexpr size_t OFF_PA = OFF_ES + 4096;             // 3,145,728 B
    constexpr size_t OFF_XB = OFF_PA + 3145728;          // 50,331,648 B

    __bf16* Wt     = (__bf16*)(ws + OFF_WT);
    float* scores3 = (float*)(ws + OFF_SC);
    float* esum    = (float*)(ws + OFF_ES);
    float* partial = (float*)(ws + OFF_PA);
    __bf16* xb     = (__bf16*)(ws + OFF_XB);

    convWX<<<dim3(576 + (Mm * Dd) / (256 * 8)), 256, 0, stream>>>(W, Wt, x, xb);
    scores_gemm<<<dim3(3 * Mm / 128), 512, 0, stream>>>(xb, Wt, v, scores3);
    pool1e<<<dim3(128, Bb), 192, 0, stream>>>(xb, scores3, partial, esum);
    pool2<<<dim3(6, Bb), 128, 0, stream>>>(partial, esum, (float*)d_out);
}

// Round 11
// 223.446 us; speedup vs baseline: 2.3013x; 2.3013x over previous
//
#include <hip/hip_runtime.h>
#include <hip/hip_bf16.h>

// Problem: B=8, S=4096, D=768
//   y = tanh(x @ W); scores = y . v; w = softmax_S(scores); out = sum_s w * x
constexpr int Bb = 8;
constexpr int Ss = 4096;
constexpr int Dd = 768;
constexpr int Mm = Bb * Ss;      // 32768 rows

typedef __bf16 bf16x8 __attribute__((ext_vector_type(8)));
typedef __bf16 bf16x4 __attribute__((ext_vector_type(4)));
typedef float f32x4 __attribute__((ext_vector_type(4)));

__device__ __forceinline__ float fast_tanh(float x) {
    return 1.f - 2.f / (__expf(2.f * x) + 1.f);
}

__device__ __forceinline__ void load_lds16(const void* g, void* l) {
    __builtin_amdgcn_global_load_lds(
        (const __attribute__((address_space(1))) unsigned int*)g,
        (__attribute__((address_space(3))) unsigned int*)l, 16, 0, 0);
}

// ---------------- Kernel 0 (merged): blocks 0..575 transpose W fp32 ->
// Wt[n][k] bf16 with the bank-swizzle baked into the layout (16B slot s ->
// s ^ ((n>>1)&3) within each 64B k-chunk; measured 0-conflict on B reads).
// blocks 576..: x fp32 -> xb bf16 with the SAME swizzle baked per-row
// (slot s -> s ^ ((m>>1)&3)) so the gemm A-read is conflict-free too.
__global__ __launch_bounds__(256) void convWX(const float* __restrict__ W,
                                              __bf16* __restrict__ Wt,
                                              const float* __restrict__ x,
                                              __bf16* __restrict__ xb) {
    const int bid = blockIdx.x;
    if (bid < 576) {                      // ---- convW tile (24 x 24 grid)
        __shared__ float tile[32][33];
        const int tx = threadIdx.x & 31;
        const int ty = threadIdx.x >> 5;
        const int kb = (bid % 24) * 32;
        const int nb = (bid / 24) * 32;
#pragma unroll
        for (int i = 0; i < 32; i += 8)
            tile[ty + i][tx] = W[(size_t)(kb + ty + i) * Dd + nb + tx];
        __syncthreads();
#pragma unroll
        for (int i = 0; i < 32; i += 8) {
            const int n = nb + ty + i;
            const int txs = (tx & 7) | ((((tx >> 3) & 3) ^ ((n >> 1) & 3)) << 3);
            Wt[(size_t)n * Dd + kb + txs] = (__bf16)tile[tx][ty + i];
        }
    } else {                              // ---- convX chunk (12288 blocks)
        const size_t i = ((size_t)(bid - 576) * 256 + threadIdx.x) * 8;
        const int m = (int)(i / Dd);
        const int k = (int)(i % Dd);
        const int sl = (k >> 3) & 3;      // logical 16B slot in 64B chunk
        const int dk = (k & ~31) | (((sl ^ ((m >> 1) & 3)) << 3));
        const float4 a = *(const float4*)(x + i);
        const float4 b = *(const float4*)(x + i + 4);
        bf16x8 p;
        p[0] = (__bf16)a.x; p[1] = (__bf16)a.y; p[2] = (__bf16)a.z; p[3] = (__bf16)a.w;
        p[4] = (__bf16)b.x; p[5] = (__bf16)b.y; p[6] = (__bf16)b.z; p[7] = (__bf16)b.w;
        *(bf16x8*)(xb + (size_t)m * Dd + dk) = p;
    }
}

// ---------------- Kernel 1: scores6[nb][m] = sum_n v[n]*tanh( (x@W)[m][n] )
// Round-11: the literal m97 geometry (874 TF proven). 256 thr = 4 waves
// (2wm x 2wn), tile BM=128 x BN=128, wave tile 64x64 (4x4 acc = 64 regs,
// UNCHANGED per-thread resources -> ~110 VGPR fits the 3-waves/SIMD budget
// of 170; round-10's 8-wave/6-waves-SIMD demand capped VGPR at 85 and
// spilled acc -> 594 MB scratch traffic, VGPR_Count 40, 6x regression).
// LDS 3-deep x (8KB A + 8KB B) + 1KB = 49 KB -> 3 blocks/CU; grid
// 256 mb x 6 nb = 1536 = exactly 2 residency rounds, ZERO tail (round-9's
// 768@2/CU ran a 1-block/CU tail for 1/3 of the work). Counted-vmcnt ledger
// kept: 4 gl_lds per step, S(k+2) in flight, vmcnt(4) steady / 0 at k=23.
// Both operands read at the baked-swizzle slot (measured 0 conflicts);
// setprio around MFMAs; XCD-bijective swizzle (1536 = 8 x 192).
__global__ __launch_bounds__(256, 3) void scores_gemm(
    const __bf16* __restrict__ xb, const __bf16* __restrict__ Wt,
    const float* __restrict__ v, float* __restrict__ scores6) {
    __shared__ __bf16 As[3][128 * 32];    // 3 x 8 KB
    __shared__ __bf16 Bs[3][128 * 32];    // 3 x 8 KB
    __shared__ float ssc[4][64];          // 1 KB   -> 49 KB total

    const int t = threadIdx.x;
    // XCD swizzle: 1536 blocks, 8 XCDs -> XCD x owns ids [x*192,(x+1)*192)
    const int id = blockIdx.x;
    const int ids = ((id & 7) * 192) + (id >> 3);
    const int mb = ids / 6;               // 0..255
    const int nb = ids - mb * 6;          // 0..5
    const int lane = t & 63;
    const int wave = t >> 6;              // 0..3
    const int wm = wave >> 1;             // 0..1 (64-row half)
    const int wn = wave & 1;              // 0..1 (64-col half)
    const int quad = lane >> 4;
    const int lid = lane & 15;
    const int rslot = ((quad ^ ((lid >> 1) & 3)) * 8);   // A+B read swizzle

    // A staging: 2 shots of 256x16B over the [128 x 64B] tile; shot j covers
    // rows j*64..j*64+63 (thread t -> row j*64 + t>>2, 16B slot t&3).
    const __bf16* axg[2];
    const __bf16* bgp[2];
    int sl_[2];
#pragma unroll
    for (int j = 0; j < 2; ++j) {
        const int row = j * 64 + (t >> 2);
        axg[j] = xb + (size_t)(mb * 128 + row) * Dd + (t & 3) * 8;
        bgp[j] = Wt + (size_t)(nb * 128 + row) * Dd + (t & 3) * 8;
        sl_[j] = j * 2048 + t * 8;        // bf16 index into As/Bs[buf]
    }

    f32x4 acc[4][4];
#pragma unroll
    for (int tm = 0; tm < 4; ++tm)
#pragma unroll
        for (int nt = 0; nt < 4; ++nt) acc[tm][nt] = (f32x4){0.f, 0.f, 0.f, 0.f};

    // ---- prologue: S(0) -> buf0, S(1) -> buf1  (8 ops in flight)
#pragma unroll
    for (int j = 0; j < 2; ++j) load_lds16(axg[j], &As[0][sl_[j]]);
#pragma unroll
    for (int j = 0; j < 2; ++j) load_lds16(bgp[j], &Bs[0][sl_[j]]);
#pragma unroll
    for (int j = 0; j < 2; ++j) load_lds16(axg[j] + 32, &As[1][sl_[j]]);
#pragma unroll
    for (int j = 0; j < 2; ++j) load_lds16(bgp[j] + 32, &Bs[1][sl_[j]]);

#pragma unroll
    for (int k = 0; k < 24; ++k) {
        // Ledger (in-order retire): outstanding = S(k)[4] + S(k+1)[4];
        // need S(k) retired, S(k+1) keeps flying -> vmcnt(4). k=23: drain.
        if (k == 23) asm volatile("s_waitcnt vmcnt(0)" ::: "memory");
        else         asm volatile("s_waitcnt vmcnt(4)" ::: "memory");
        __builtin_amdgcn_sched_barrier(0);
        __builtin_amdgcn_s_barrier();     // publish buf k
        __builtin_amdgcn_sched_barrier(0);

        if (k < 22) {                     // S(k+2), 2-step flight
#pragma unroll
            for (int j = 0; j < 2; ++j)
                load_lds16(axg[j] + (k + 2) * 32, &As[(k + 2) % 3][sl_[j]]);
#pragma unroll
            for (int j = 0; j < 2; ++j)
                load_lds16(bgp[j] + (k + 2) * 32, &Bs[(k + 2) % 3][sl_[j]]);
        }
        __builtin_amdgcn_sched_barrier(0);

        bf16x8 af[4], bfr[4];
#pragma unroll
        for (int tm = 0; tm < 4; ++tm)
            af[tm] = *(const bf16x8*)(&As[k % 3][(wm * 64 + tm * 16 + lid) * 32 + rslot]);
#pragma unroll
        for (int nt = 0; nt < 4; ++nt)
            bfr[nt] = *(const bf16x8*)(&Bs[k % 3][(wn * 64 + nt * 16 + lid) * 32 + rslot]);

        __builtin_amdgcn_s_setprio(1);
#pragma unroll
        for (int tm = 0; tm < 4; ++tm)
#pragma unroll
            for (int nt = 0; nt < 4; ++nt)
                acc[tm][nt] = __builtin_amdgcn_mfma_f32_16x16x32_bf16(af[tm], bfr[nt], acc[tm][nt], 0, 0, 0);
        __builtin_amdgcn_s_setprio(0);
    }

    // ---- epilogue: fold tanh*v over this block's 128 cols, reduce to rows
    float vv[4];
#pragma unroll
    for (int nt = 0; nt < 4; ++nt)
        vv[nt] = v[nb * 128 + wn * 64 + nt * 16 + lid];

#pragma unroll
    for (int tm = 0; tm < 4; ++tm)
#pragma unroll
        for (int r = 0; r < 4; ++r) {
            float s = 0.f;
#pragma unroll
            for (int nt = 0; nt < 4; ++nt) s += vv[nt] * fast_tanh(acc[tm][nt][r]);
            // C layout: col=lid, row=quad*4+r
            s += __shfl_xor(s, 1);
            s += __shfl_xor(s, 2);
            s += __shfl_xor(s, 4);
            s += __shfl_xor(s, 8);
            if (lid == 0) ssc[wave][tm * 16 + quad * 4 + r] = s;
        }
    __syncthreads();
    if (t < 128) {
        const int wmh = t >> 6;           // which 64-row half
        const int rl = t & 63;
        const float s = ssc[wmh * 2 + 0][rl] + ssc[wmh * 2 + 1][rl];
        scores6[(size_t)nb * Mm + mb * 128 + t] = s;   // no atomics, no memset
    }
}

// ---------------- Kernel 2: pool with INLINE exp (no separate softmax pass,
// no fences/atomics). Scores structurally bounded (|s| <= ||v||_1 ~ 6.2) so
// exp without max-subtraction is fp32-safe (verified rounds 7-10). Reads xb
// (bf16, 50 MB; swizzle undone via XOR on the read index, coalescing kept).
// Sums the 6 n-split score partials.
__global__ __launch_bounds__(192) void pool1e(const __bf16* __restrict__ xb,
                                              const float* __restrict__ scores6,
                                              float* __restrict__ partial,
                                              float* __restrict__ esum) {
    const int b = blockIdx.y;
    const int c = blockIdx.x;            // 128 chunks x 32 rows
    const int t = threadIdx.x;           // owns 4 d-cols at d0 = t*4
    __shared__ float we[32];

    if (t < 32) {
        const size_t i = (size_t)b * Ss + c * 32 + t;
        float sc = 0.f;
#pragma unroll
        for (int j = 0; j < 6; ++j) sc += scores6[i + (size_t)j * Mm];
        we[t] = __expf(sc);
    }
    __syncthreads();

    const int d0 = t * 4;
    const int kc = d0 & ~31;             // 64B-chunk base (32 bf16)
    const int sl = (d0 >> 3) & 3;        // logical 16B slot
    const int w8 = d0 & 7;               // offset within slot (0 or 4)
    const int m0 = b * Ss + c * 32;      // global row of i=0
    const __bf16* base = xb + (size_t)m0 * Dd;

    float4 acc = make_float4(0.f, 0.f, 0.f, 0.f);
#pragma unroll 8
    for (int i = 0; i < 32; ++i) {
        const float ww = we[i];
        const int phys = kc + ((sl ^ (((m0 + i) >> 1) & 3)) << 3) + w8;
        const bf16x4 xv = *(const bf16x4*)(base + (size_t)i * Dd + phys);
        acc.x += ww * (float)xv[0];
        acc.y += ww * (float)xv[1];
        acc.z += ww * (float)xv[2];
        acc.w += ww * (float)xv[3];
    }
    *(float4*)(partial + ((size_t)(b * 128 + c)) * Dd + d0) = acc;
    if (t == 0) {
        float s = 0.f;
#pragma unroll
        for (int i = 0; i < 32; ++i) s += we[i];
        esum[b * 128 + c] = s;
    }
}

// ---------------- Kernel 3: out[b][d] = (sum_c partial[b][c][d]) / sum esum.
// grid (6 d-segments, B) = 48 blocks x 128 thr; each block also reduces the
// 128 esums for its batch (tiny, L2-hit).
__global__ __launch_bounds__(128) void pool2(const float* __restrict__ partial,
                                             const float* __restrict__ esum,
                                             float* __restrict__ out) {
    const int b = blockIdx.y;
    const int t = threadIdx.x;
    const int d = blockIdx.x * 128 + t;   // 0..767

    float es = 0.f;
    if (t < 64) {
        es = esum[b * 128 + t] + esum[b * 128 + 64 + t];
        es += __shfl_xor(es, 1);
        es += __shfl_xor(es, 2);
        es += __shfl_xor(es, 4);
        es += __shfl_xor(es, 8);
        es += __shfl_xor(es, 16);
        es += __shfl_xor(es, 32);
    }
    __shared__ float esT;
    if (t == 0) esT = es;
    __syncthreads();
    const float inv = 1.f / esT;

    float s = 0.f;
#pragma unroll 8
    for (int c = 0; c < 128; ++c) s += partial[((size_t)(b * 128 + c)) * Dd + d];
    out[(size_t)b * Dd + d] = s * inv;
}

extern "C" void kernel_launch(void* const* d_in, const int* in_sizes, int n_in,
                              void* d_out, int out_size, void* d_ws, size_t ws_size,
                              hipStream_t stream) {
    (void)in_sizes; (void)n_in; (void)ws_size; (void)out_size;
    const float* x = (const float*)d_in[0];
    const float* v = (const float*)d_in[1];
    const float* W = (const float*)d_in[2];

    char* ws = (char*)d_ws;
    // layout: Wt | scores6 | esum | partial | xb   (~56 MB)
    constexpr size_t OFF_WT = 0;                         // 1,179,648 B
    constexpr size_t OFF_SC = 1179648;                   //   786,432 B (6 x 32768 f32)
    constexpr size_t OFF_ES = OFF_SC + 786432;           //     4,096 B
    constexpr size_t OFF_PA = OFF_ES + 4096;             // 3,145,728 B
    constexpr size_t OFF_XB = OFF_PA + 3145728;          // 50,331,648 B

    __bf16* Wt     = (__bf16*)(ws + OFF_WT);
    float* scores6 = (float*)(ws + OFF_SC);
    float* esum    = (float*)(ws + OFF_ES);
    float* partial = (float*)(ws + OFF_PA);
    __bf16* xb     = (__bf16*)(ws + OFF_XB);

    convWX<<<dim3(576 + (Mm * Dd) / (256 * 8)), 256, 0, stream>>>(W, Wt, x, xb);
    scores_gemm<<<dim3(6 * Mm / 128), 256, 0, stream>>>(xb, Wt, v, scores6);
    pool1e<<<dim3(128, Bb), 192, 0, stream>>>(xb, scores6, partial, esum);
    pool2<<<dim3(6, Bb), 128, 0, stream>>>(partial, esum, (float*)d_out);
}

// Round 12
// 220.169 us; speedup vs baseline: 2.3356x; 1.0149x over previous
//
#include <hip/hip_runtime.h>
#include <hip/hip_bf16.h>

// Problem: B=8, S=4096, D=768
//   y = tanh(x @ W); scores = y . v; w = softmax_S(scores); out = sum_s w * x
constexpr int Bb = 8;
constexpr int Ss = 4096;
constexpr int Dd = 768;
constexpr int Mm = Bb * Ss;      // 32768 rows

typedef __bf16 bf16x8 __attribute__((ext_vector_type(8)));
typedef __bf16 bf16x4 __attribute__((ext_vector_type(4)));
typedef float f32x4 __attribute__((ext_vector_type(4)));

__device__ __forceinline__ float fast_tanh(float x) {
    return 1.f - 2.f / (__expf(2.f * x) + 1.f);
}

__device__ __forceinline__ void load_lds16(const void* g, void* l) {
    __builtin_amdgcn_global_load_lds(
        (const __attribute__((address_space(1))) unsigned int*)g,
        (__attribute__((address_space(3))) unsigned int*)l, 16, 0, 0);
}

// ---------------- Kernel 0 (merged): blocks 0..575 transpose W fp32 ->
// Wt[n][k] bf16 with the bank-swizzle baked into the layout (16B slot s ->
// s ^ ((n>>1)&3) within each 64B k-chunk; measured 0-conflict on B reads).
// blocks 576..: x fp32 -> xb bf16 with the SAME swizzle baked per-row
// (slot s -> s ^ ((m>>1)&3)) so the gemm A-read is conflict-free too
// (fixed the measured 2,359,296 conflict-cycles of linear xb in round 9).
__global__ __launch_bounds__(256) void convWX(const float* __restrict__ W,
                                              __bf16* __restrict__ Wt,
                                              const float* __restrict__ x,
                                              __bf16* __restrict__ xb) {
    const int bid = blockIdx.x;
    if (bid < 576) {                      // ---- convW tile (24 x 24 grid)
        __shared__ float tile[32][33];
        const int tx = threadIdx.x & 31;
        const int ty = threadIdx.x >> 5;
        const int kb = (bid % 24) * 32;
        const int nb = (bid / 24) * 32;
#pragma unroll
        for (int i = 0; i < 32; i += 8)
            tile[ty + i][tx] = W[(size_t)(kb + ty + i) * Dd + nb + tx];
        __syncthreads();
#pragma unroll
        for (int i = 0; i < 32; i += 8) {
            const int n = nb + ty + i;
            const int txs = (tx & 7) | ((((tx >> 3) & 3) ^ ((n >> 1) & 3)) << 3);
            Wt[(size_t)n * Dd + kb + txs] = (__bf16)tile[tx][ty + i];
        }
    } else {                              // ---- convX chunk (12288 blocks)
        const size_t i = ((size_t)(bid - 576) * 256 + threadIdx.x) * 8;
        const int m = (int)(i / Dd);
        const int k = (int)(i % Dd);
        const int sl = (k >> 3) & 3;      // logical 16B slot in 64B chunk
        const int dk = (k & ~31) | (((sl ^ ((m >> 1) & 3)) << 3));
        const float4 a = *(const float4*)(x + i);
        const float4 b = *(const float4*)(x + i + 4);
        bf16x8 p;
        p[0] = (__bf16)a.x; p[1] = (__bf16)a.y; p[2] = (__bf16)a.z; p[3] = (__bf16)a.w;
        p[4] = (__bf16)b.x; p[5] = (__bf16)b.y; p[6] = (__bf16)b.z; p[7] = (__bf16)b.w;
        *(bf16x8*)(xb + (size_t)m * Dd + dk) = p;
    }
}

// ---------------- Kernel 1: scores3[nb][m] = sum_n v[n]*tanh( (x@W)[m][n] )
// ROUND-9 CHAMPION VERBATIM (the fastest measured gemm config, <58us; the
// two structural alternatives both regressed: R10 8w@3/CU spilled acc to
// scratch, R11 4w/BN=128 doubled barrier-steps -> 62.7us). BM=128 x BN=256,
// n-split 3, 8 waves (2wm x 4wn), wave tile 64x64; per K-step 3 gl_lds +
// 8 ds_read_b128 + 16 MFMA; 3-deep LDS; counted vmcnt(3) never 0 in-loop;
// one barrier per step; setprio; XCD-bijective swizzle; both operands read
// at the baked-swizzle slot (measured 0 bank conflicts).
__global__ __launch_bounds__(512, 4) void scores_gemm(
    const __bf16* __restrict__ xb, const __bf16* __restrict__ Wt,
    const float* __restrict__ v, float* __restrict__ scores3) {
    __shared__ __bf16 As[3][128 * 32];    // 3 x 8 KB
    __shared__ __bf16 Bs[3][256 * 32];    // 3 x 16 KB
    __shared__ float ssc[8][64];          // 2 KB

    const int t = threadIdx.x;
    // XCD swizzle: 768 blocks, 8 XCDs -> XCD x owns ids [x*96,(x+1)*96)
    const int id = blockIdx.x;
    const int ids = ((id & 7) * 96) + (id >> 3);
    const int mb = ids / 3;               // 0..255
    const int nb = ids - mb * 3;          // 0..2
    const int lane = t & 63;
    const int wave = t >> 6;
    const int wm = wave >> 2;             // 0..1 (64-row half)
    const int wn = wave & 3;              // 0..3 (64-col slice)
    const int quad = lane >> 4;
    const int lid = lane & 15;
    const int rslot = ((quad ^ ((lid >> 1) & 3)) * 8);   // A+B read swizzle

    // A staging: 1 shot of 512x16B over the [128 x 64B] tile (xb stored in
    // phys-slot order -> linear gl_lds source).
    const __bf16* axg = xb + (size_t)(mb * 128 + (t >> 2)) * Dd + (t & 3) * 8;
    const int awl = t * 8;                // bf16 index into As[buf]

    // B staging: 2 shots of 512x16B over the [256 x 64B] tile.
    const __bf16* bgp[2];
    int blp[2];
#pragma unroll
    for (int j = 0; j < 2; ++j) {
        const int flat = j * 8192 + t * 16;   // bytes
        const int col = flat >> 6;
        bgp[j] = Wt + (size_t)(nb * 256 + col) * Dd + ((flat & 63) >> 1);
        blp[j] = flat >> 1;                   // bf16 index into Bs[buf]
    }

    f32x4 acc[4][4];
#pragma unroll
    for (int tm = 0; tm < 4; ++tm)
#pragma unroll
        for (int nt = 0; nt < 4; ++nt) acc[tm][nt] = (f32x4){0.f, 0.f, 0.f, 0.f};

    // ---- prologue: S(0)=[A0,B0,B0]; S(1)=[A1,B1,B1]  (6 ops in flight)
    load_lds16(axg, &As[0][awl]);
#pragma unroll
    for (int j = 0; j < 2; ++j) load_lds16(bgp[j], &Bs[0][blp[j]]);
    load_lds16(axg + 32, &As[1][awl]);
#pragma unroll
    for (int j = 0; j < 2; ++j) load_lds16(bgp[j] + 32, &Bs[1][blp[j]]);

#pragma unroll
    for (int k = 0; k < 24; ++k) {
        // Ledger (in-order retire): outstanding = S(k)[3] + S(k+1)[3];
        // need S(k) retired, S(k+1) keeps flying -> vmcnt(3). k=23: drain.
        if (k == 23) asm volatile("s_waitcnt vmcnt(0)" ::: "memory");
        else         asm volatile("s_waitcnt vmcnt(3)" ::: "memory");
        __builtin_amdgcn_sched_barrier(0);
        __builtin_amdgcn_s_barrier();     // publish buf k
        __builtin_amdgcn_sched_barrier(0);

        if (k < 22) {                     // S(k+2), 2-step flight
            load_lds16(axg + (k + 2) * 32, &As[(k + 2) % 3][awl]);
#pragma unroll
            for (int j = 0; j < 2; ++j)
                load_lds16(bgp[j] + (k + 2) * 32, &Bs[(k + 2) % 3][blp[j]]);
        }
        __builtin_amdgcn_sched_barrier(0);

        bf16x8 af[4], bfr[4];
#pragma unroll
        for (int tm = 0; tm < 4; ++tm)
            af[tm] = *(const bf16x8*)(&As[k % 3][(wm * 64 + tm * 16 + lid) * 32 + rslot]);
#pragma unroll
        for (int nt = 0; nt < 4; ++nt)
            bfr[nt] = *(const bf16x8*)(&Bs[k % 3][(wn * 64 + nt * 16 + lid) * 32 + rslot]);

        __builtin_amdgcn_s_setprio(1);
#pragma unroll
        for (int tm = 0; tm < 4; ++tm)
#pragma unroll
            for (int nt = 0; nt < 4; ++nt)
                acc[tm][nt] = __builtin_amdgcn_mfma_f32_16x16x32_bf16(af[tm], bfr[nt], acc[tm][nt], 0, 0, 0);
        __builtin_amdgcn_s_setprio(0);
    }

    // ---- epilogue: fold tanh*v over this block's 256 cols, reduce to rows
    float vv[4];
#pragma unroll
    for (int nt = 0; nt < 4; ++nt)
        vv[nt] = v[nb * 256 + wn * 64 + nt * 16 + lid];

#pragma unroll
    for (int tm = 0; tm < 4; ++tm)
#pragma unroll
        for (int r = 0; r < 4; ++r) {
            float s = 0.f;
#pragma unroll
            for (int nt = 0; nt < 4; ++nt) s += vv[nt] * fast_tanh(acc[tm][nt][r]);
            // C layout: col=lid, row=quad*4+r
            s += __shfl_xor(s, 1);
            s += __shfl_xor(s, 2);
            s += __shfl_xor(s, 4);
            s += __shfl_xor(s, 8);
            if (lid == 0) ssc[wave][tm * 16 + quad * 4 + r] = s;
        }
    __syncthreads();
    if (t < 128) {
        const int wmh = t >> 6;           // which 64-row half
        const int rl = t & 63;
        float s = 0.f;
#pragma unroll
        for (int ww = 0; ww < 4; ++ww) s += ssc[wmh * 4 + ww][rl];
        scores3[(size_t)nb * Mm + mb * 128 + t] = s;   // no atomics, no memset
    }
}

// ---------------- Kernel 2: pool with INLINE exp (no separate softmax pass,
// no fences/atomics). Scores structurally bounded (|s| <= ||v||_1 ~ 6.2) so
// exp without max-subtraction is fp32-safe (verified rounds 7-11). Reads xb
// (bf16, 50 MB). NEW vs round 9: the de-swizzle XOR is CONST-FOLDED — since
// m0 = b*4096+c*32 is a multiple of 32, ((m0+i)>>1)&3 == ((i>>1)&3), which
// is compile-time inside the unrolled loop. Removes ~96 VALU ops/iter-group
// and folds the offsets into the load immediates.
__global__ __launch_bounds__(192) void pool1e(const __bf16* __restrict__ xb,
                                              const float* __restrict__ scores3,
                                              float* __restrict__ partial,
                                              float* __restrict__ esum) {
    const int b = blockIdx.y;
    const int c = blockIdx.x;            // 128 chunks x 32 rows
    const int t = threadIdx.x;           // owns 4 d-cols at d0 = t*4
    __shared__ float we[32];

    if (t < 32) {
        const size_t i = (size_t)b * Ss + c * 32 + t;
        we[t] = __expf(scores3[i] + scores3[Mm + i] + scores3[2 * Mm + i]);
    }
    __syncthreads();

    const int d0 = t * 4;
    const int kc = d0 & ~31;             // 64B-chunk base (32 bf16)
    const int sl = (d0 >> 3) & 3;        // logical 16B slot
    const int w8 = d0 & 7;               // offset within slot (0 or 4)
    const int m0 = b * Ss + c * 32;      // multiple of 32
    const __bf16* base = xb + (size_t)m0 * Dd;

    float4 acc = make_float4(0.f, 0.f, 0.f, 0.f);
#pragma unroll
    for (int i = 0; i < 32; ++i) {
        const float ww = we[i];
        // m0 % 32 == 0 -> ((m0+i)>>1)&3 == (i>>1)&3 (compile-time per i)
        const int phys = kc + ((sl ^ ((i >> 1) & 3)) << 3) + w8;
        const bf16x4 xv = *(const bf16x4*)(base + (size_t)i * Dd + phys);
        acc.x += ww * (float)xv[0];
        acc.y += ww * (float)xv[1];
        acc.z += ww * (float)xv[2];
        acc.w += ww * (float)xv[3];
    }
    *(float4*)(partial + ((size_t)(b * 128 + c)) * Dd + d0) = acc;
    if (t == 0) {
        float s = 0.f;
#pragma unroll
        for (int i = 0; i < 32; ++i) s += we[i];
        esum[b * 128 + c] = s;
    }
}

// ---------------- Kernel 3: out[b][d] = (sum_c partial[b][c][d]) / sum esum.
// grid (6 d-segments, B) = 48 blocks x 128 thr; each block also reduces the
// 128 esums for its batch (tiny, L2-hit).
__global__ __launch_bounds__(128) void pool2(const float* __restrict__ partial,
                                             const float* __restrict__ esum,
                                             float* __restrict__ out) {
    const int b = blockIdx.y;
    const int t = threadIdx.x;
    const int d = blockIdx.x * 128 + t;   // 0..767

    float es = 0.f;
    if (t < 64) {
        es = esum[b * 128 + t] + esum[b * 128 + 64 + t];
        es += __shfl_xor(es, 1);
        es += __shfl_xor(es, 2);
        es += __shfl_xor(es, 4);
        es += __shfl_xor(es, 8);
        es += __shfl_xor(es, 16);
        es += __shfl_xor(es, 32);
    }
    __shared__ float esT;
    if (t == 0) esT = es;
    __syncthreads();
    const float inv = 1.f / esT;

    float s = 0.f;
#pragma unroll 8
    for (int c = 0; c < 128; ++c) s += partial[((size_t)(b * 128 + c)) * Dd + d];
    out[(size_t)b * Dd + d] = s * inv;
}

extern "C" void kernel_launch(void* const* d_in, const int* in_sizes, int n_in,
                              void* d_out, int out_size, void* d_ws, size_t ws_size,
                              hipStream_t stream) {
    (void)in_sizes; (void)n_in; (void)ws_size; (void)out_size;
    const float* x = (const float*)d_in[0];
    const float* v = (const float*)d_in[1];
    const float* W = (const float*)d_in[2];

    char* ws = (char*)d_ws;
    // layout: Wt | scores3 | esum | partial | xb   (~55 MB)
    constexpr size_t OFF_WT = 0;                         // 1,179,648 B
    constexpr size_t OFF_SC = 1179648;                   //   393,216 B
    constexpr size_t OFF_ES = OFF_SC + 393216;           //     4,096 B
    constexpr size_t OFF_PA = OFF_ES + 4096;             // 3,145,728 B
    constexpr size_t OFF_XB = OFF_PA + 3145728;          // 50,331,648 B

    __bf16* Wt     = (__bf16*)(ws + OFF_WT);
    float* scores3 = (float*)(ws + OFF_SC);
    float* esum    = (float*)(ws + OFF_ES);
    float* partial = (float*)(ws + OFF_PA);
    __bf16* xb     = (__bf16*)(ws + OFF_XB);

    convWX<<<dim3(576 + (Mm * Dd) / (256 * 8)), 256, 0, stream>>>(W, Wt, x, xb);
    scores_gemm<<<dim3(3 * Mm / 128), 512, 0, stream>>>(xb, Wt, v, scores3);
    pool1e<<<dim3(128, Bb), 192, 0, stream>>>(xb, scores3, partial, esum);
    pool2<<<dim3(6, Bb), 128, 0, stream>>>(partial, esum, (float*)d_out);
}